// Round 8
// baseline (228.099 us; speedup 1.0000x reference)
//
#include <hip/hip_runtime.h>
#include <hip/hip_bf16.h>

// Problem constants
#define BB 2
#define TT 2048
#define CC 768
#define HH 12
#define DD 64
#define NQKV 2304           // 3*H*D
#define MTOT (BB*TT)        // 4096
#define CH 32               // scan chunk rows
#define NCH (TT/CH)         // 64 chunks

typedef __bf16 bf16x8 __attribute__((ext_vector_type(8)));
typedef __bf16 bf16x4 __attribute__((ext_vector_type(4)));
typedef float  f32x4  __attribute__((ext_vector_type(4)));

__device__ __forceinline__ f32x4 mfma16(bf16x8 a, bf16x8 b, f32x4 c) {
    return __builtin_amdgcn_mfma_f32_16x16x32_bf16(a, b, c, 0, 0, 0);
}

__device__ __forceinline__ void load_lds16(const void* g, void* l) {
    __builtin_amdgcn_global_load_lds(
        (const __attribute__((address_space(1))) void*)g,
        (__attribute__((address_space(3))) void*)l, 16, 0, 0);
}

// ---------------------------------------------------------------------------
// 1) f32 -> bf16 convert for x, w_attn, w_proj
// ---------------------------------------------------------------------------
__global__ __launch_bounds__(256) void cvt_bf16_kernel(
    const float* __restrict__ x, const float* __restrict__ wa, const float* __restrict__ wp,
    __bf16* __restrict__ xb, __bf16* __restrict__ wab, __bf16* __restrict__ wpb)
{
    const long NX = (long)MTOT * CC;       // 3,145,728
    const long NWA = (long)NQKV * CC;      // 1,769,472
    long idx = ((long)blockIdx.x * 256 + threadIdx.x) * 4;
    const float* src; __bf16* dst; long off;
    if (idx < NX)            { src = x;  dst = xb;  off = idx; }
    else if (idx < NX + NWA) { src = wa; dst = wab; off = idx - NX; }
    else                     { src = wp; dst = wpb; off = idx - NX - NWA; }
    float4 v = *(const float4*)(src + off);
    bf16x4 o;
    o[0] = (__bf16)v.x; o[1] = (__bf16)v.y; o[2] = (__bf16)v.z; o[3] = (__bf16)v.w;
    *(bf16x4*)(dst + off) = o;
}

// ---------------------------------------------------------------------------
// 2) NT GEMM (A[M,K] row-major, B[N,K] row-major), 128x128 tile, BK=32,
//    global_load_lds staging. EPI=0: bf16 C row-major (qkv). EPI=1: f32 C.
//    Epilogue is plain coalesced row-major stores — no scatter, no div.
// ---------------------------------------------------------------------------
template<int EPI>
__global__ __launch_bounds__(256, 2) void gemm_nt_kernel(
    const __bf16* __restrict__ A, const __bf16* __restrict__ Bw,
    const float* __restrict__ bias,
    __bf16* __restrict__ oBF, float* __restrict__ oF32, int K)
{
    __shared__ __align__(16) __bf16 As[128 * 32];
    __shared__ __align__(16) __bf16 Bs[128 * 32];
    const int tid = threadIdx.x;
    const int m0 = blockIdx.y * 128, n0 = blockIdx.x * 128;
    const int w = tid >> 6, lane = tid & 63, quad = lane >> 4, l16 = lane & 15;
    const int wm = (w >> 1) * 64, wn = (w & 1) * 64;
    const int grow = w * 16 + (lane >> 2);
    const int gcol = (lane & 3) * 8;
    __bf16* AsW = As + w * 512;
    __bf16* BsW = Bs + w * 512;

    f32x4 acc[4][4] = {};

    for (int kt = 0; kt < K; kt += 32) {
        __syncthreads();
        load_lds16(A  + (long)(m0 + grow) * K + kt + gcol,      AsW);
        load_lds16(A  + (long)(m0 + grow + 64) * K + kt + gcol, AsW + 2048);
        load_lds16(Bw + (long)(n0 + grow) * K + kt + gcol,      BsW);
        load_lds16(Bw + (long)(n0 + grow + 64) * K + kt + gcol, BsW + 2048);
        __syncthreads();

        bf16x8 af[4], bfr[4];
#pragma unroll
        for (int g = 0; g < 4; g++)  af[g]  = *(const bf16x8*)(As + (wm + g * 16 + l16) * 32 + quad * 8);
#pragma unroll
        for (int jb = 0; jb < 4; jb++) bfr[jb] = *(const bf16x8*)(Bs + (wn + jb * 16 + l16) * 32 + quad * 8);
#pragma unroll
        for (int g = 0; g < 4; g++)
#pragma unroll
            for (int jb = 0; jb < 4; jb++)
                acc[g][jb] = mfma16(af[g], bfr[jb], acc[g][jb]);
    }

    // epilogue: C/D layout col = lane&15, row = quad*4 + reg; row-major stores
    const int ldc = (EPI == 0) ? NQKV : CC;
#pragma unroll
    for (int jb = 0; jb < 4; jb++) {
        const int n = n0 + wn + jb * 16 + l16;
        const float bv = bias[n];
#pragma unroll
        for (int g = 0; g < 4; g++) {
#pragma unroll
            for (int r = 0; r < 4; r++) {
                const int m = m0 + wm + g * 16 + quad * 4 + r;
                const float v = acc[g][jb][r] + bv;
                if (EPI == 0) oBF[(long)m * ldc + n] = (__bf16)v;
                else          oF32[(long)m * ldc + n] = v;
            }
        }
    }
}

// ---------------------------------------------------------------------------
// 2b) V transpose: qkv[b,t,1536+h*64+d] -> vT[(b*H+h)*64+d][t], LDS-tiled.
// ---------------------------------------------------------------------------
__global__ __launch_bounds__(256) void transpose_v_kernel(
    const __bf16* __restrict__ qkv, __bf16* __restrict__ vT)
{
    __shared__ __bf16 Tl[64][72];     // [d][t] (+pad)
    const int tt = blockIdx.x, h = blockIdx.y, b = blockIdx.z;
    const int tid = threadIdx.x;
    const int r8 = tid >> 3, c8 = (tid & 7) * 8;
    const __bf16* src = qkv + (long)(b * TT + tt * 64) * NQKV + 1536 + h * 64;
#pragma unroll
    for (int p = 0; p < 2; p++) {
        const int row = p * 32 + r8;                     // t within tile
        bf16x8 v = *(const bf16x8*)(src + (long)row * NQKV + c8);
#pragma unroll
        for (int e = 0; e < 8; e++) Tl[c8 + e][row] = v[e];
    }
    __syncthreads();
    __bf16* dst = vT + ((long)(b * HH + h) << 6) * TT + tt * 64;
#pragma unroll
    for (int p = 0; p < 2; p++) {
        const int d = p * 32 + r8;
        *(bf16x8*)(dst + (long)d * TT + c8) = *(const bf16x8*)(&Tl[d][c8]);
    }
}

// ---------------------------------------------------------------------------
// 3) Head-0 selection scores, bf16 out: S[b,i,j] = (1<=j<i) ? relu(qk*0.125) : 0
//    q from qkv cols 0..63, k from qkv cols 768..831 (h=0).
// ---------------------------------------------------------------------------
__global__ __launch_bounds__(256) void sgemm_kernel(
    const __bf16* __restrict__ qkv, __bf16* __restrict__ S)
{
    const int tj = blockIdx.x, ti = blockIdx.y, b = blockIdx.z;
    if (tj > ti) return;
    const int w = threadIdx.x >> 6, lane = threadIdx.x & 63, quad = lane >> 4, l16 = lane & 15;
    const int i0 = ti * 64 + w * 16;

    const __bf16* qp = qkv + (long)(b * TT + i0 + l16) * NQKV + quad * 8;
    bf16x8 a0 = *(const bf16x8*)qp, a1 = *(const bf16x8*)(qp + 32);
    const __bf16* kbase = qkv + (long)(b * TT) * NQKV + 768;

#pragma unroll
    for (int jb = 0; jb < 4; jb++) {
        const __bf16* kp = kbase + (long)(tj * 64 + jb * 16 + l16) * NQKV + quad * 8;
        bf16x8 b0 = *(const bf16x8*)kp, b1 = *(const bf16x8*)(kp + 32);
        f32x4 acc = {};
        acc = mfma16(a0, b0, acc);
        acc = mfma16(a1, b1, acc);
        const int j = tj * 64 + jb * 16 + l16;
#pragma unroll
        for (int r = 0; r < 4; r++) {
            const int i = i0 + quad * 4 + r;
            float v = fmaxf(acc[r] * 0.125f, 0.0f);
            v = (j >= 1 && j < i) ? v : 0.0f;
            S[((long)b * TT + i) * TT + j] = (__bf16)v;
        }
    }
}

// ---------------------------------------------------------------------------
// 4) Exclusive cumsum over query dim, per column j: 2 kernels (prefix folded
//    into scan_write: each block sums its predecessor chunk-sums directly).
// ---------------------------------------------------------------------------
__global__ __launch_bounds__(256) void scan_sum_kernel(
    const __bf16* __restrict__ S, float* __restrict__ csum)
{
    const int j = blockIdx.x * 256 + threadIdx.x;
    const int chunk = blockIdx.y, b = blockIdx.z;
    const int ib = chunk * CH;
    const __bf16* p = S + ((long)b * TT + ib) * TT + j;
    float s = 0.0f;
#pragma unroll
    for (int ii = 0; ii < CH; ii++) {
        float v = (float)p[(long)ii * TT];
        s += ((ib + ii) > j) ? v : 0.0f;
    }
    csum[(b * NCH + chunk) * TT + j] = s;
}

__global__ __launch_bounds__(256) void scan_write_kernel(
    const __bf16* __restrict__ S, const float* __restrict__ csum, __bf16* __restrict__ Fo)
{
    const int j = blockIdx.x * 256 + threadIdx.x;
    const int chunk = blockIdx.y, b = blockIdx.z;
    const int ib = chunk * CH;
    float off = 0.0f;
    for (int c = 0; c < chunk; c++) off += csum[(b * NCH + c) * TT + j];
    const __bf16* ps = S  + ((long)b * TT + ib) * TT + j;
    __bf16*       pf = Fo + ((long)b * TT + ib) * TT + j;
#pragma unroll
    for (int ii = 0; ii < CH; ii++) {
        float v = ((ib + ii) > j) ? (float)ps[(long)ii * TT] : 0.0f;
        pf[(long)ii * TT] = (__bf16)off;   // exclusive: write before add
        off += v;
    }
}

// ---------------------------------------------------------------------------
// 5) Flash attention with F subtraction. v8 = v7 structure (single-barrier
//    dbuf pipeline, paired q-tiles {bid, 63-bid}), q/k read from qkv strided.
// ---------------------------------------------------------------------------
__global__ __launch_bounds__(128, 2) void flash_kernel(
    const __bf16* __restrict__ qkv, const __bf16* __restrict__ vT,
    const __bf16* __restrict__ F, __bf16* __restrict__ y)
{
    __shared__ __align__(16) __bf16 Ks[2][64 * 64];
    __shared__ __align__(16) __bf16 Vs[2][64 * 64];
    __shared__ __align__(16) __bf16 Pls[2][16 * 72];
    const int bid = blockIdx.x, h = blockIdx.y, b = blockIdx.z;
    const int w = threadIdx.x >> 6, lane = threadIdx.x & 63, quad = lane >> 4, l16 = lane & 15;
    const int rl = lane >> 3;                 // DMA: row-in-group 0..7
    const int cs8 = ((lane & 7) ^ rl) * 8;    // DMA: swizzled source col offset
    const int sw0 = ((quad)     ^ (l16 & 7)) * 8;   // reader swizzle
    const int sw1 = ((quad + 4) ^ (l16 & 7)) * 8;
    __bf16* Pl = &Pls[w][0];
    const __bf16* kb = qkv + (long)(b * TT) * NQKV + 768 + h * 64;   // + j*NQKV
    const __bf16* vb = vT + ((long)(b * HH + h) << 6) * TT;          // [d][t]
    const __bf16* Fbase = F + (long)b * TT * TT;

    const int qt0 = bid, qt1 = 63 - bid;      // paired q-tiles: constant work
    const int n0 = (qt0 >> 1) + 1, n1 = (qt1 >> 1) + 1;
    const int N = n0 + n1;

    int i0 = qt0 * 32 + w * 16;
    const __bf16* qp = qkv + (long)(b * TT + i0 + l16) * NQKV + h * 64 + quad * 8;
    bf16x8 aq0 = *(const bf16x8*)qp;
    bf16x8 aq1 = *(const bf16x8*)(qp + 32);

    f32x4 O[4] = {};
    float lr[4] = {0.0f, 0.0f, 0.0f, 0.0f};
    __bf16 Fn[4][4];

    // ---- prologue: stage it=0 (phase 0, jt=0) + F(it=0) ----
    {
        __bf16* KsW = Ks[0] + w * 2048;
        __bf16* VsW = Vs[0] + w * 2048;
#pragma unroll
        for (int t = 0; t < 4; t++)
            load_lds16(kb + (long)(w * 32 + t * 8 + rl) * NQKV + cs8, KsW + t * 512);
#pragma unroll
        for (int t = 0; t < 4; t++)
            load_lds16(vb + (long)(w * 32 + t * 8 + rl) * TT + cs8, VsW + t * 512);
        const __bf16* Fb = Fbase + (long)i0 * TT;
#pragma unroll
        for (int jh = 0; jh < 4; jh++)
#pragma unroll
            for (int r = 0; r < 4; r++)
                Fn[jh][r] = Fb[(long)(quad * 4 + r) * TT + jh * 16 + l16];
    }

    for (int it = 0; it < N; it++) {
        const int ph = (it >= n0);
        const int jt = (it - (ph ? n0 : 0)) << 6;
        const int qt = ph ? qt1 : qt0;
        const int jtend = (qt >> 1) << 6;

        __syncthreads();   // drains staging of Ks/Vs[it&1] + Fn loads

        __bf16 Fc[4][4];
#pragma unroll
        for (int jh = 0; jh < 4; jh++)
#pragma unroll
            for (int r = 0; r < 4; r++)
                Fc[jh][r] = Fn[jh][r];

        // ---- issue next iter's staging + F (in flight through compute) ----
        if (it + 1 < N) {
            const int ph2 = (it + 1 >= n0);
            const int jt2 = ((it + 1) - (ph2 ? n0 : 0)) << 6;
            __bf16* KsW = Ks[(it + 1) & 1] + w * 2048;
            __bf16* VsW = Vs[(it + 1) & 1] + w * 2048;
#pragma unroll
            for (int t = 0; t < 4; t++)
                load_lds16(kb + (long)(jt2 + w * 32 + t * 8 + rl) * NQKV + cs8, KsW + t * 512);
#pragma unroll
            for (int t = 0; t < 4; t++)
                load_lds16(vb + (long)(w * 32 + t * 8 + rl) * TT + jt2 + cs8, VsW + t * 512);
            const int i0n = (ph2 ? qt1 : qt0) * 32 + w * 16;
            const __bf16* Fb2 = Fbase + (long)i0n * TT;
#pragma unroll
            for (int jh = 0; jh < 4; jh++)
#pragma unroll
                for (int r = 0; r < 4; r++)
                    Fn[jh][r] = Fb2[(long)(quad * 4 + r) * TT + jt2 + jh * 16 + l16];
        }
        __builtin_amdgcn_sched_barrier(0);   // pin issue point

        // ---- QK from LDS (cur buffer) ----
        const __bf16* Kc = Ks[it & 1];
        const __bf16* Vc = Vs[it & 1];
        float sc[4][4];
#pragma unroll
        for (int jh = 0; jh < 4; jh++) {
            const int jr = jh * 16 + l16;
            const bf16x8 kc0 = *(const bf16x8*)(Kc + (jr << 6) + sw0);
            const bf16x8 kc1 = *(const bf16x8*)(Kc + (jr << 6) + sw1);
            f32x4 acc = {};
            acc = mfma16(aq0, kc0, acc);
            acc = mfma16(aq1, kc1, acc);
#pragma unroll
            for (int r = 0; r < 4; r++) sc[jh][r] = acc[r];
        }
        // ---- softmax terms ----
        if (jt == jtend) {           // diagonal tile: causal mask
#pragma unroll
            for (int jh = 0; jh < 4; jh++) {
                const int j = jt + jh * 16 + l16;
#pragma unroll
                for (int r = 0; r < 4; r++) {
                    const int i = i0 + quad * 4 + r;
                    float v = fmaf(sc[jh][r], 0.125f, -(float)Fc[jh][r]);
                    v = (j <= i) ? v : -35.0f;
                    const float p = __expf(v);
                    sc[jh][r] = p;
                    lr[r] += p;
                }
            }
        } else {
#pragma unroll
            for (int jh = 0; jh < 4; jh++) {
#pragma unroll
                for (int r = 0; r < 4; r++) {
                    float v = fmaf(sc[jh][r], 0.125f, -(float)Fc[jh][r]);
                    const float p = __expf(v);
                    sc[jh][r] = p;
                    lr[r] += p;
                }
            }
        }
        // ---- P -> LDS (C-layout -> row-major), wave-private ----
#pragma unroll
        for (int r = 0; r < 4; r++) {
            const int il = quad * 4 + r;
#pragma unroll
            for (int jh = 0; jh < 4; jh++)
                Pl[il * 72 + jh * 16 + l16] = (__bf16)sc[jh][r];
        }
        const bf16x8 ap0 = *(const bf16x8*)(Pl + l16 * 72 + quad * 8);
        const bf16x8 ap1 = *(const bf16x8*)(Pl + l16 * 72 + 32 + quad * 8);
        // ---- PV from LDS (cur buffer) ----
#pragma unroll
        for (int db = 0; db < 4; db++) {
            const bf16x8 vv0 = *(const bf16x8*)(Vc + ((db * 16 + l16) << 6) + sw0);
            const bf16x8 vv1 = *(const bf16x8*)(Vc + ((db * 16 + l16) << 6) + sw1);
            O[db] = mfma16(ap0, vv0, O[db]);
            O[db] = mfma16(ap1, vv1, O[db]);
        }
        // ---- phase end: finalize + reset ----
        if (jt == jtend) {
            float inv[4];
#pragma unroll
            for (int r = 0; r < 4; r++) {
                float s = lr[r];
#pragma unroll
                for (int off = 8; off >= 1; off >>= 1) s += __shfl_xor(s, off, 16);
                inv[r] = 1.0f / s;
            }
#pragma unroll
            for (int db = 0; db < 4; db++) {
#pragma unroll
                for (int r = 0; r < 4; r++) {
                    const int i = i0 + quad * 4 + r;
                    y[((long)(b * TT + i)) * (HH * DD) + h * 64 + db * 16 + l16] = (__bf16)(O[db][r] * inv[r]);
                }
            }
#pragma unroll
            for (int db = 0; db < 4; db++) { O[db][0] = 0.f; O[db][1] = 0.f; O[db][2] = 0.f; O[db][3] = 0.f; }
            lr[0] = lr[1] = lr[2] = lr[3] = 0.0f;
            if (!ph) {   // switch to phase-1 q-tile
                i0 = qt1 * 32 + w * 16;
                const __bf16* qp2 = qkv + (long)(b * TT + i0 + l16) * NQKV + h * 64 + quad * 8;
                aq0 = *(const bf16x8*)qp2;
                aq1 = *(const bf16x8*)(qp2 + 32);
            }
        }
    }
}

// ---------------------------------------------------------------------------
extern "C" void kernel_launch(void* const* d_in, const int* in_sizes, int n_in,
                              void* d_out, int out_size, void* d_ws, size_t ws_size,
                              hipStream_t stream)
{
    const float* x      = (const float*)d_in[0];
    const float* w_attn = (const float*)d_in[1];
    const float* b_attn = (const float*)d_in[2];
    const float* w_proj = (const float*)d_in[3];
    const float* b_proj = (const float*)d_in[4];
    float* out = (float*)d_out;

    char* ws = (char*)d_ws;
    __bf16* xb   = (__bf16*)ws; ws += (long)MTOT * CC * 2;
    __bf16* wab  = (__bf16*)ws; ws += (long)NQKV * CC * 2;
    __bf16* wpb  = (__bf16*)ws; ws += (long)CC * (HH*DD) * 2;
    __bf16* qkvb = (__bf16*)ws; ws += (long)MTOT * NQKV * 2;        // 18.9 MB
    __bf16* vtb  = (__bf16*)ws; ws += (long)BB * HH * TT * DD * 2;
    __bf16* SF   = (__bf16*)ws; ws += (long)BB * TT * TT * 2;       // S (bf16)
    __bf16* Fo   = (__bf16*)ws; ws += (long)BB * TT * TT * 2;       // F (bf16)
    float*  cs   = (float*)ws;  ws += (long)BB * NCH * TT * 4;
    __bf16* yb   = (__bf16*)ws; ws += (long)MTOT * (HH*DD) * 2;

    // 1) convert inputs to bf16
    cvt_bf16_kernel<<<5376, 256, 0, stream>>>(x, w_attn, w_proj, xb, wab, wpb);
    // 2) QKV projection -> qkv row-major (bf16, coalesced epilogue)
    gemm_nt_kernel<0><<<dim3(NQKV / 128, MTOT / 128), 256, 0, stream>>>(
        xb, wab, b_attn, qkvb, nullptr, CC);
    // 2b) V transpose -> vT[b,h,d,t]
    transpose_v_kernel<<<dim3(TT / 64, HH, BB), 256, 0, stream>>>(qkvb, vtb);
    // 3) head-0 selection scores S (bf16)
    sgemm_kernel<<<dim3(TT / 64, TT / 64, BB), 256, 0, stream>>>(qkvb, SF);
    // 4) exclusive cumsum over query dim -> F (bf16), 2-pass (prefix folded)
    scan_sum_kernel<<<dim3(TT / 256, NCH, BB), 256, 0, stream>>>(SF, cs);
    scan_write_kernel<<<dim3(TT / 256, NCH, BB), 256, 0, stream>>>(SF, cs, Fo);
    // 5) flash attention with F subtraction -> y (bf16)
    flash_kernel<<<dim3(32, HH, BB), 128, 0, stream>>>(qkvb, vtb, Fo, yb);
    // 6) output projection -> out (f32)
    gemm_nt_kernel<1><<<dim3(CC / 128, MTOT / 128), 256, 0, stream>>>(
        yb, wpb, b_proj, nullptr, out, HH * DD);
}

// Round 9
// 221.539 us; speedup vs baseline: 1.0296x; 1.0296x over previous
//
#include <hip/hip_runtime.h>
#include <hip/hip_bf16.h>

// Problem constants
#define BB 2
#define TT 2048
#define CC 768
#define HH 12
#define DD 64
#define NQKV 2304           // 3*H*D
#define MTOT (BB*TT)        // 4096
#define CH 32               // scan chunk rows
#define NCH (TT/CH)         // 64 chunks

typedef __bf16 bf16x8 __attribute__((ext_vector_type(8)));
typedef __bf16 bf16x4 __attribute__((ext_vector_type(4)));
typedef float  f32x4  __attribute__((ext_vector_type(4)));

__device__ __forceinline__ f32x4 mfma16(bf16x8 a, bf16x8 b, f32x4 c) {
    return __builtin_amdgcn_mfma_f32_16x16x32_bf16(a, b, c, 0, 0, 0);
}

__device__ __forceinline__ void load_lds16(const void* g, void* l) {
    __builtin_amdgcn_global_load_lds(
        (const __attribute__((address_space(1))) void*)g,
        (__attribute__((address_space(3))) void*)l, 16, 0, 0);
}

// ---------------------------------------------------------------------------
// 1) f32 -> bf16 convert for x, w_attn, w_proj
// ---------------------------------------------------------------------------
__global__ __launch_bounds__(256) void cvt_bf16_kernel(
    const float* __restrict__ x, const float* __restrict__ wa, const float* __restrict__ wp,
    __bf16* __restrict__ xb, __bf16* __restrict__ wab, __bf16* __restrict__ wpb)
{
    const long NX = (long)MTOT * CC;       // 3,145,728
    const long NWA = (long)NQKV * CC;      // 1,769,472
    long idx = ((long)blockIdx.x * 256 + threadIdx.x) * 4;
    const float* src; __bf16* dst; long off;
    if (idx < NX)            { src = x;  dst = xb;  off = idx; }
    else if (idx < NX + NWA) { src = wa; dst = wab; off = idx - NX; }
    else                     { src = wp; dst = wpb; off = idx - NX - NWA; }
    float4 v = *(const float4*)(src + off);
    bf16x4 o;
    o[0] = (__bf16)v.x; o[1] = (__bf16)v.y; o[2] = (__bf16)v.z; o[3] = (__bf16)v.w;
    *(bf16x4*)(dst + off) = o;
}

// ---------------------------------------------------------------------------
// 2) NT GEMM (A[M,K] row-major, B[N,K] row-major), 128x128 tile, BK=32,
//    global_load_lds staging. EPI=0: bf16 C row-major (qkv). EPI=1: f32 C.
// ---------------------------------------------------------------------------
template<int EPI>
__global__ __launch_bounds__(256, 2) void gemm_nt_kernel(
    const __bf16* __restrict__ A, const __bf16* __restrict__ Bw,
    const float* __restrict__ bias,
    __bf16* __restrict__ oBF, float* __restrict__ oF32, int K)
{
    __shared__ __align__(16) __bf16 As[128 * 32];
    __shared__ __align__(16) __bf16 Bs[128 * 32];
    const int tid = threadIdx.x;
    const int m0 = blockIdx.y * 128, n0 = blockIdx.x * 128;
    const int w = tid >> 6, lane = tid & 63, quad = lane >> 4, l16 = lane & 15;
    const int wm = (w >> 1) * 64, wn = (w & 1) * 64;
    const int grow = w * 16 + (lane >> 2);
    const int gcol = (lane & 3) * 8;
    __bf16* AsW = As + w * 512;
    __bf16* BsW = Bs + w * 512;

    f32x4 acc[4][4] = {};

    for (int kt = 0; kt < K; kt += 32) {
        __syncthreads();
        load_lds16(A  + (long)(m0 + grow) * K + kt + gcol,      AsW);
        load_lds16(A  + (long)(m0 + grow + 64) * K + kt + gcol, AsW + 2048);
        load_lds16(Bw + (long)(n0 + grow) * K + kt + gcol,      BsW);
        load_lds16(Bw + (long)(n0 + grow + 64) * K + kt + gcol, BsW + 2048);
        __syncthreads();

        bf16x8 af[4], bfr[4];
#pragma unroll
        for (int g = 0; g < 4; g++)  af[g]  = *(const bf16x8*)(As + (wm + g * 16 + l16) * 32 + quad * 8);
#pragma unroll
        for (int jb = 0; jb < 4; jb++) bfr[jb] = *(const bf16x8*)(Bs + (wn + jb * 16 + l16) * 32 + quad * 8);
#pragma unroll
        for (int g = 0; g < 4; g++)
#pragma unroll
            for (int jb = 0; jb < 4; jb++)
                acc[g][jb] = mfma16(af[g], bfr[jb], acc[g][jb]);
    }

    // epilogue: C/D layout col = lane&15, row = quad*4 + reg; row-major stores
    const int ldc = (EPI == 0) ? NQKV : CC;
#pragma unroll
    for (int jb = 0; jb < 4; jb++) {
        const int n = n0 + wn + jb * 16 + l16;
        const float bv = bias[n];
#pragma unroll
        for (int g = 0; g < 4; g++) {
#pragma unroll
            for (int r = 0; r < 4; r++) {
                const int m = m0 + wm + g * 16 + quad * 4 + r;
                const float v = acc[g][jb][r] + bv;
                if (EPI == 0) oBF[(long)m * ldc + n] = (__bf16)v;
                else          oF32[(long)m * ldc + n] = v;
            }
        }
    }
}

// ---------------------------------------------------------------------------
// 2b) V transpose: qkv[b,t,1536+h*64+d] -> vT[(b*H+h)*64+d][t], LDS-tiled.
// ---------------------------------------------------------------------------
__global__ __launch_bounds__(256) void transpose_v_kernel(
    const __bf16* __restrict__ qkv, __bf16* __restrict__ vT)
{
    __shared__ __bf16 Tl[64][72];     // [d][t] (+pad)
    const int tt = blockIdx.x, h = blockIdx.y, b = blockIdx.z;
    const int tid = threadIdx.x;
    const int r8 = tid >> 3, c8 = (tid & 7) * 8;
    const __bf16* src = qkv + (long)(b * TT + tt * 64) * NQKV + 1536 + h * 64;
#pragma unroll
    for (int p = 0; p < 2; p++) {
        const int row = p * 32 + r8;                     // t within tile
        bf16x8 v = *(const bf16x8*)(src + (long)row * NQKV + c8);
#pragma unroll
        for (int e = 0; e < 8; e++) Tl[c8 + e][row] = v[e];
    }
    __syncthreads();
    __bf16* dst = vT + ((long)(b * HH + h) << 6) * TT + tt * 64;
#pragma unroll
    for (int p = 0; p < 2; p++) {
        const int d = p * 32 + r8;
        *(bf16x8*)(dst + (long)d * TT + c8) = *(const bf16x8*)(&Tl[d][c8]);
    }
}

// ---------------------------------------------------------------------------
// 3) Head-0 selection scores + fused chunk-sums.
//    S[b,i,j] = (1<=j<i) ? relu(qk*0.125) : 0 (bf16), and
//    csum[b,c,j] += sum of S over rows in chunk c (each 32-row chunk lies
//    entirely inside one 64-row tile -> block-local, via quad-shuffle +
//    16-lane atomicAdd). Replaces the scan_sum kernel.
// ---------------------------------------------------------------------------
__global__ __launch_bounds__(256) void sgemm_kernel(
    const __bf16* __restrict__ qkv, __bf16* __restrict__ S, float* __restrict__ csum)
{
    const int tj = blockIdx.x, ti = blockIdx.y, b = blockIdx.z;
    if (tj > ti) return;
    const int w = threadIdx.x >> 6, lane = threadIdx.x & 63, quad = lane >> 4, l16 = lane & 15;
    const int i0 = ti * 64 + w * 16;
    const int chunk = ti * 2 + (w >> 1);     // this wave's 16 rows lie in this chunk

    const __bf16* qp = qkv + (long)(b * TT + i0 + l16) * NQKV + quad * 8;
    bf16x8 a0 = *(const bf16x8*)qp, a1 = *(const bf16x8*)(qp + 32);
    const __bf16* kbase = qkv + (long)(b * TT) * NQKV + 768;

#pragma unroll
    for (int jb = 0; jb < 4; jb++) {
        const __bf16* kp = kbase + (long)(tj * 64 + jb * 16 + l16) * NQKV + quad * 8;
        bf16x8 b0 = *(const bf16x8*)kp, b1 = *(const bf16x8*)(kp + 32);
        f32x4 acc = {};
        acc = mfma16(a0, b0, acc);
        acc = mfma16(a1, b1, acc);
        const int j = tj * 64 + jb * 16 + l16;
        float colsum = 0.0f;
#pragma unroll
        for (int r = 0; r < 4; r++) {
            const int i = i0 + quad * 4 + r;
            float v = fmaxf(acc[r] * 0.125f, 0.0f);
            v = (j >= 1 && j < i) ? v : 0.0f;
            S[((long)b * TT + i) * TT + j] = (__bf16)v;
            colsum += v;
        }
        // reduce over quads (same j in each l16 slot) -> 16-row column sum
        colsum += __shfl_xor(colsum, 16);
        colsum += __shfl_xor(colsum, 32);
        if (quad == 0)
            atomicAdd(&csum[((long)b * NCH + chunk) * TT + j], colsum);
    }
}

// ---------------------------------------------------------------------------
// 4) Exclusive cumsum over query dim: scan_write only (prefix of chunk-sums
//    folded in). Early-exit for j-blocks entirely right of the chunk (F there
//    is never read unmasked by flash; 0xAA poison decodes to finite junk).
// ---------------------------------------------------------------------------
__global__ __launch_bounds__(256) void scan_write_kernel(
    const __bf16* __restrict__ S, const float* __restrict__ csum, __bf16* __restrict__ Fo)
{
    const int chunk = blockIdx.y, b = blockIdx.z;
    const int ib = chunk * CH;
    const int j0 = blockIdx.x * 256;
    if (j0 >= ib + CH) return;                 // F[j > i] never read unmasked
    const int j = j0 + threadIdx.x;
    float off = 0.0f;
    for (int c = 0; c < chunk; c++) off += csum[((long)b * NCH + c) * TT + j];
    const __bf16* ps = S  + ((long)b * TT + ib) * TT + j;
    __bf16*       pf = Fo + ((long)b * TT + ib) * TT + j;
#pragma unroll
    for (int ii = 0; ii < CH; ii++) {
        float v = ((ib + ii) > j) ? (float)ps[(long)ii * TT] : 0.0f;
        pf[(long)ii * TT] = (__bf16)off;   // exclusive: write before add
        off += v;
    }
}

// ---------------------------------------------------------------------------
// 5) Flash attention with F subtraction. v9 = v8 structure + XCD-CLUSTERED
//    grid: flat 768 blocks; gid&7 = presumed XCD slot; the 32 paired blocks
//    of one (b,h) group land on ONE XCD so its 512 KB K/V footprint stays
//    L2-resident (3 groups x 1.5 MB per 4 MB XCD-L2). If the %8 dispatch
//    heuristic is wrong this is a perf no-op, not a correctness issue.
// ---------------------------------------------------------------------------
__global__ __launch_bounds__(128, 2) void flash_kernel(
    const __bf16* __restrict__ qkv, const __bf16* __restrict__ vT,
    const __bf16* __restrict__ F, __bf16* __restrict__ y)
{
    __shared__ __align__(16) __bf16 Ks[2][64 * 64];
    __shared__ __align__(16) __bf16 Vs[2][64 * 64];
    __shared__ __align__(16) __bf16 Pls[2][16 * 72];
    const int gid = blockIdx.x;
    const int xs = gid & 7, s = gid >> 3;
    const int gi = xs + ((s >> 5) << 3);      // (b,h) group 0..23, const per XCD-slot
    const int bid = s & 31;
    const int h = gi % 12, b = gi / 12;
    const int w = threadIdx.x >> 6, lane = threadIdx.x & 63, quad = lane >> 4, l16 = lane & 15;
    const int rl = lane >> 3;                 // DMA: row-in-group 0..7
    const int cs8 = ((lane & 7) ^ rl) * 8;    // DMA: swizzled source col offset
    const int sw0 = ((quad)     ^ (l16 & 7)) * 8;   // reader swizzle
    const int sw1 = ((quad + 4) ^ (l16 & 7)) * 8;
    __bf16* Pl = &Pls[w][0];
    const __bf16* kb = qkv + (long)(b * TT) * NQKV + 768 + h * 64;   // + j*NQKV
    const __bf16* vb = vT + ((long)(b * HH + h) << 6) * TT;          // [d][t]
    const __bf16* Fbase = F + (long)b * TT * TT;

    const int qt0 = bid, qt1 = 63 - bid;      // paired q-tiles: constant work
    const int n0 = (qt0 >> 1) + 1, n1 = (qt1 >> 1) + 1;
    const int N = n0 + n1;

    int i0 = qt0 * 32 + w * 16;
    const __bf16* qp = qkv + (long)(b * TT + i0 + l16) * NQKV + h * 64 + quad * 8;
    bf16x8 aq0 = *(const bf16x8*)qp;
    bf16x8 aq1 = *(const bf16x8*)(qp + 32);

    f32x4 O[4] = {};
    float lr[4] = {0.0f, 0.0f, 0.0f, 0.0f};
    __bf16 Fn[4][4];

    // ---- prologue: stage it=0 (phase 0, jt=0) + F(it=0) ----
    {
        __bf16* KsW = Ks[0] + w * 2048;
        __bf16* VsW = Vs[0] + w * 2048;
#pragma unroll
        for (int t = 0; t < 4; t++)
            load_lds16(kb + (long)(w * 32 + t * 8 + rl) * NQKV + cs8, KsW + t * 512);
#pragma unroll
        for (int t = 0; t < 4; t++)
            load_lds16(vb + (long)(w * 32 + t * 8 + rl) * TT + cs8, VsW + t * 512);
        const __bf16* Fb = Fbase + (long)i0 * TT;
#pragma unroll
        for (int jh = 0; jh < 4; jh++)
#pragma unroll
            for (int r = 0; r < 4; r++)
                Fn[jh][r] = Fb[(long)(quad * 4 + r) * TT + jh * 16 + l16];
    }

    for (int it = 0; it < N; it++) {
        const int ph = (it >= n0);
        const int jt = (it - (ph ? n0 : 0)) << 6;
        const int qt = ph ? qt1 : qt0;
        const int jtend = (qt >> 1) << 6;

        __syncthreads();   // drains staging of Ks/Vs[it&1] + Fn loads

        __bf16 Fc[4][4];
#pragma unroll
        for (int jh = 0; jh < 4; jh++)
#pragma unroll
            for (int r = 0; r < 4; r++)
                Fc[jh][r] = Fn[jh][r];

        // ---- issue next iter's staging + F (in flight through compute) ----
        if (it + 1 < N) {
            const int ph2 = (it + 1 >= n0);
            const int jt2 = ((it + 1) - (ph2 ? n0 : 0)) << 6;
            __bf16* KsW = Ks[(it + 1) & 1] + w * 2048;
            __bf16* VsW = Vs[(it + 1) & 1] + w * 2048;
#pragma unroll
            for (int t = 0; t < 4; t++)
                load_lds16(kb + (long)(jt2 + w * 32 + t * 8 + rl) * NQKV + cs8, KsW + t * 512);
#pragma unroll
            for (int t = 0; t < 4; t++)
                load_lds16(vb + (long)(w * 32 + t * 8 + rl) * TT + jt2 + cs8, VsW + t * 512);
            const int i0n = (ph2 ? qt1 : qt0) * 32 + w * 16;
            const __bf16* Fb2 = Fbase + (long)i0n * TT;
#pragma unroll
            for (int jh = 0; jh < 4; jh++)
#pragma unroll
                for (int r = 0; r < 4; r++)
                    Fn[jh][r] = Fb2[(long)(quad * 4 + r) * TT + jt2 + jh * 16 + l16];
        }
        __builtin_amdgcn_sched_barrier(0);   // pin issue point

        // ---- QK from LDS (cur buffer) ----
        const __bf16* Kc = Ks[it & 1];
        const __bf16* Vc = Vs[it & 1];
        float sc[4][4];
#pragma unroll
        for (int jh = 0; jh < 4; jh++) {
            const int jr = jh * 16 + l16;
            const bf16x8 kc0 = *(const bf16x8*)(Kc + (jr << 6) + sw0);
            const bf16x8 kc1 = *(const bf16x8*)(Kc + (jr << 6) + sw1);
            f32x4 acc = {};
            acc = mfma16(aq0, kc0, acc);
            acc = mfma16(aq1, kc1, acc);
#pragma unroll
            for (int r = 0; r < 4; r++) sc[jh][r] = acc[r];
        }
        // ---- softmax terms ----
        if (jt == jtend) {           // diagonal tile: causal mask
#pragma unroll
            for (int jh = 0; jh < 4; jh++) {
                const int j = jt + jh * 16 + l16;
#pragma unroll
                for (int r = 0; r < 4; r++) {
                    const int i = i0 + quad * 4 + r;
                    float v = fmaf(sc[jh][r], 0.125f, -(float)Fc[jh][r]);
                    v = (j <= i) ? v : -35.0f;
                    const float p = __expf(v);
                    sc[jh][r] = p;
                    lr[r] += p;
                }
            }
        } else {
#pragma unroll
            for (int jh = 0; jh < 4; jh++) {
#pragma unroll
                for (int r = 0; r < 4; r++) {
                    float v = fmaf(sc[jh][r], 0.125f, -(float)Fc[jh][r]);
                    const float p = __expf(v);
                    sc[jh][r] = p;
                    lr[r] += p;
                }
            }
        }
        // ---- P -> LDS (C-layout -> row-major), wave-private ----
#pragma unroll
        for (int r = 0; r < 4; r++) {
            const int il = quad * 4 + r;
#pragma unroll
            for (int jh = 0; jh < 4; jh++)
                Pl[il * 72 + jh * 16 + l16] = (__bf16)sc[jh][r];
        }
        const bf16x8 ap0 = *(const bf16x8*)(Pl + l16 * 72 + quad * 8);
        const bf16x8 ap1 = *(const bf16x8*)(Pl + l16 * 72 + 32 + quad * 8);
        // ---- PV from LDS (cur buffer) ----
#pragma unroll
        for (int db = 0; db < 4; db++) {
            const bf16x8 vv0 = *(const bf16x8*)(Vc + ((db * 16 + l16) << 6) + sw0);
            const bf16x8 vv1 = *(const bf16x8*)(Vc + ((db * 16 + l16) << 6) + sw1);
            O[db] = mfma16(ap0, vv0, O[db]);
            O[db] = mfma16(ap1, vv1, O[db]);
        }
        // ---- phase end: finalize + reset ----
        if (jt == jtend) {
            float inv[4];
#pragma unroll
            for (int r = 0; r < 4; r++) {
                float s2 = lr[r];
#pragma unroll
                for (int off = 8; off >= 1; off >>= 1) s2 += __shfl_xor(s2, off, 16);
                inv[r] = 1.0f / s2;
            }
#pragma unroll
            for (int db = 0; db < 4; db++) {
#pragma unroll
                for (int r = 0; r < 4; r++) {
                    const int i = i0 + quad * 4 + r;
                    y[((long)(b * TT + i)) * (HH * DD) + h * 64 + db * 16 + l16] = (__bf16)(O[db][r] * inv[r]);
                }
            }
#pragma unroll
            for (int db = 0; db < 4; db++) { O[db][0] = 0.f; O[db][1] = 0.f; O[db][2] = 0.f; O[db][3] = 0.f; }
            lr[0] = lr[1] = lr[2] = lr[3] = 0.0f;
            if (!ph) {   // switch to phase-1 q-tile
                i0 = qt1 * 32 + w * 16;
                const __bf16* qp2 = qkv + (long)(b * TT + i0 + l16) * NQKV + h * 64 + quad * 8;
                aq0 = *(const bf16x8*)qp2;
                aq1 = *(const bf16x8*)(qp2 + 32);
            }
        }
    }
}

// ---------------------------------------------------------------------------
extern "C" void kernel_launch(void* const* d_in, const int* in_sizes, int n_in,
                              void* d_out, int out_size, void* d_ws, size_t ws_size,
                              hipStream_t stream)
{
    const float* x      = (const float*)d_in[0];
    const float* w_attn = (const float*)d_in[1];
    const float* b_attn = (const float*)d_in[2];
    const float* w_proj = (const float*)d_in[3];
    const float* b_proj = (const float*)d_in[4];
    float* out = (float*)d_out;

    char* ws = (char*)d_ws;
    __bf16* xb   = (__bf16*)ws; ws += (long)MTOT * CC * 2;
    __bf16* wab  = (__bf16*)ws; ws += (long)NQKV * CC * 2;
    __bf16* wpb  = (__bf16*)ws; ws += (long)CC * (HH*DD) * 2;
    __bf16* qkvb = (__bf16*)ws; ws += (long)MTOT * NQKV * 2;        // 18.9 MB
    __bf16* vtb  = (__bf16*)ws; ws += (long)BB * HH * TT * DD * 2;
    __bf16* SF   = (__bf16*)ws; ws += (long)BB * TT * TT * 2;       // S (bf16)
    __bf16* Fo   = (__bf16*)ws; ws += (long)BB * TT * TT * 2;       // F (bf16)
    float*  cs   = (float*)ws;  ws += (long)BB * NCH * TT * 4;      // 1 MB
    __bf16* yb   = (__bf16*)ws; ws += (long)MTOT * (HH*DD) * 2;

    // 0) zero csum (accumulated atomically by sgemm)
    hipMemsetAsync(cs, 0, (long)BB * NCH * TT * 4, stream);
    // 1) convert inputs to bf16
    cvt_bf16_kernel<<<5376, 256, 0, stream>>>(x, w_attn, w_proj, xb, wab, wpb);
    // 2) QKV projection -> qkv row-major (bf16)
    gemm_nt_kernel<0><<<dim3(NQKV / 128, MTOT / 128), 256, 0, stream>>>(
        xb, wab, b_attn, qkvb, nullptr, CC);
    // 2b) V transpose -> vT[b,h,d,t]
    transpose_v_kernel<<<dim3(TT / 64, HH, BB), 256, 0, stream>>>(qkvb, vtb);
    // 3) head-0 selection scores S (bf16) + fused chunk-sums -> csum
    sgemm_kernel<<<dim3(TT / 64, TT / 64, BB), 256, 0, stream>>>(qkvb, SF, cs);
    // 4) exclusive cumsum over query dim -> F (bf16), single pass
    scan_write_kernel<<<dim3(TT / 256, NCH, BB), 256, 0, stream>>>(SF, cs, Fo);
    // 5) flash attention with F subtraction -> y (bf16); XCD-clustered grid
    flash_kernel<<<dim3(768), 128, 0, stream>>>(qkvb, vtb, Fo, yb);
    // 6) output projection -> out (f32)
    gemm_nt_kernel<1><<<dim3(CC / 128, MTOT / 128), 256, 0, stream>>>(
        yb, wpb, b_proj, nullptr, out, HH * DD);
}

// Round 10
// 208.151 us; speedup vs baseline: 1.0958x; 1.0643x over previous
//
#include <hip/hip_runtime.h>
#include <hip/hip_bf16.h>

// Problem constants
#define BB 2
#define TT 2048
#define CC 768
#define HH 12
#define DD 64
#define NQKV 2304           // 3*H*D
#define MTOT (BB*TT)        // 4096
#define CH 32               // scan chunk rows
#define NCH (TT/CH)         // 64 chunks

typedef __bf16 bf16x8 __attribute__((ext_vector_type(8)));
typedef __bf16 bf16x4 __attribute__((ext_vector_type(4)));
typedef float  f32x4  __attribute__((ext_vector_type(4)));

__device__ __forceinline__ f32x4 mfma16(bf16x8 a, bf16x8 b, f32x4 c) {
    return __builtin_amdgcn_mfma_f32_16x16x32_bf16(a, b, c, 0, 0, 0);
}

__device__ __forceinline__ void load_lds16(const void* g, void* l) {
    __builtin_amdgcn_global_load_lds(
        (const __attribute__((address_space(1))) void*)g,
        (__attribute__((address_space(3))) void*)l, 16, 0, 0);
}

// ---------------------------------------------------------------------------
// 1) f32 -> bf16 convert for x, w_attn, w_proj + csum zeroing (fused memset)
// ---------------------------------------------------------------------------
__global__ __launch_bounds__(256) void cvt_bf16_kernel(
    const float* __restrict__ x, const float* __restrict__ wa, const float* __restrict__ wp,
    __bf16* __restrict__ xb, __bf16* __restrict__ wab, __bf16* __restrict__ wpb,
    float* __restrict__ cs)
{
    const long NX = (long)MTOT * CC;       // 3,145,728
    const long NWA = (long)NQKV * CC;      // 1,769,472
    const long NWP = (long)CC * (HH*DD);   // 589,824
    const long NTOT = NX + NWA + NWP;      // 5,505,024
    long idx = ((long)blockIdx.x * 256 + threadIdx.x) * 4;
    if (idx >= NTOT) {                     // tail blocks: zero csum (1 MB)
        float4 z = {0.f, 0.f, 0.f, 0.f};
        *(float4*)(cs + (idx - NTOT)) = z;
        return;
    }
    const float* src; __bf16* dst; long off;
    if (idx < NX)            { src = x;  dst = xb;  off = idx; }
    else if (idx < NX + NWA) { src = wa; dst = wab; off = idx - NX; }
    else                     { src = wp; dst = wpb; off = idx - NX - NWA; }
    float4 v = *(const float4*)(src + off);
    bf16x4 o;
    o[0] = (__bf16)v.x; o[1] = (__bf16)v.y; o[2] = (__bf16)v.z; o[3] = (__bf16)v.w;
    *(bf16x4*)(dst + off) = o;
}

// ---------------------------------------------------------------------------
// 2) NT GEMM (A[M,K] row-major, B[N,K] row-major), 128x128 tile, BK=32,
//    global_load_lds staging. EPI=0: q/k thirds -> qkv row-major (bf16),
//    v third -> vT[b,h,d,t] via packed 8B stores (fused transpose).
//    EPI=1: f32 C row-major.
// ---------------------------------------------------------------------------
template<int EPI>
__global__ __launch_bounds__(256, 2) void gemm_nt_kernel(
    const __bf16* __restrict__ A, const __bf16* __restrict__ Bw,
    const float* __restrict__ bias,
    __bf16* __restrict__ oQKV, __bf16* __restrict__ oVT,
    float* __restrict__ oF32, int K)
{
    __shared__ __align__(16) __bf16 As[128 * 32];
    __shared__ __align__(16) __bf16 Bs[128 * 32];
    const int tid = threadIdx.x;
    const int m0 = blockIdx.y * 128, n0 = blockIdx.x * 128;
    const int w = tid >> 6, lane = tid & 63, quad = lane >> 4, l16 = lane & 15;
    const int wm = (w >> 1) * 64, wn = (w & 1) * 64;
    const int grow = w * 16 + (lane >> 2);
    const int gcol = (lane & 3) * 8;
    __bf16* AsW = As + w * 512;
    __bf16* BsW = Bs + w * 512;

    f32x4 acc[4][4] = {};

    for (int kt = 0; kt < K; kt += 32) {
        __syncthreads();
        load_lds16(A  + (long)(m0 + grow) * K + kt + gcol,      AsW);
        load_lds16(A  + (long)(m0 + grow + 64) * K + kt + gcol, AsW + 2048);
        load_lds16(Bw + (long)(n0 + grow) * K + kt + gcol,      BsW);
        load_lds16(Bw + (long)(n0 + grow + 64) * K + kt + gcol, BsW + 2048);
        __syncthreads();

        bf16x8 af[4], bfr[4];
#pragma unroll
        for (int g = 0; g < 4; g++)  af[g]  = *(const bf16x8*)(As + (wm + g * 16 + l16) * 32 + quad * 8);
#pragma unroll
        for (int jb = 0; jb < 4; jb++) bfr[jb] = *(const bf16x8*)(Bs + (wn + jb * 16 + l16) * 32 + quad * 8);
#pragma unroll
        for (int g = 0; g < 4; g++)
#pragma unroll
            for (int jb = 0; jb < 4; jb++)
                acc[g][jb] = mfma16(af[g], bfr[jb], acc[g][jb]);
    }

    // epilogue: C/D layout col = lane&15, row = quad*4 + reg
#pragma unroll
    for (int jb = 0; jb < 4; jb++) {
        const int n = n0 + wn + jb * 16 + l16;
        const float bv = bias[n];
        if (EPI == 1) {
#pragma unroll
            for (int g = 0; g < 4; g++)
#pragma unroll
                for (int r = 0; r < 4; r++) {
                    const int m = m0 + wm + g * 16 + quad * 4 + r;
                    oF32[(long)m * CC + n] = acc[g][jb][r] + bv;
                }
        } else {
            const int which = n / 768;          // uniform within (jb)
            if (which < 2) {                    // q/k -> qkv row-major
#pragma unroll
                for (int g = 0; g < 4; g++)
#pragma unroll
                    for (int r = 0; r < 4; r++) {
                        const int m = m0 + wm + g * 16 + quad * 4 + r;
                        oQKV[(long)m * NQKV + n] = (__bf16)(acc[g][jb][r] + bv);
                    }
            } else {                            // v -> vT[b,h,d,t], 8B packed
                const int rem = n - 1536, hh = rem >> 6, d = rem & 63;
#pragma unroll
                for (int g = 0; g < 4; g++) {
                    const int m = m0 + wm + g * 16 + quad * 4;
                    const int b = m >> 11, t = m & 2047;
                    bf16x4 pk;
#pragma unroll
                    for (int r = 0; r < 4; r++) pk[r] = (__bf16)(acc[g][jb][r] + bv);
                    *(bf16x4*)(oVT + ((long)(((b * HH + hh) << 6) + d)) * TT + t) = pk;
                }
            }
        }
    }
}

// ---------------------------------------------------------------------------
// 3) Head-0 selection scores + fused chunk-sums (quad-shuffle + atomicAdd).
// ---------------------------------------------------------------------------
__global__ __launch_bounds__(256) void sgemm_kernel(
    const __bf16* __restrict__ qkv, __bf16* __restrict__ S, float* __restrict__ csum)
{
    const int tj = blockIdx.x, ti = blockIdx.y, b = blockIdx.z;
    if (tj > ti) return;
    const int w = threadIdx.x >> 6, lane = threadIdx.x & 63, quad = lane >> 4, l16 = lane & 15;
    const int i0 = ti * 64 + w * 16;
    const int chunk = ti * 2 + (w >> 1);     // this wave's 16 rows lie in this chunk

    const __bf16* qp = qkv + (long)(b * TT + i0 + l16) * NQKV + quad * 8;
    bf16x8 a0 = *(const bf16x8*)qp, a1 = *(const bf16x8*)(qp + 32);
    const __bf16* kbase = qkv + (long)(b * TT) * NQKV + 768;

#pragma unroll
    for (int jb = 0; jb < 4; jb++) {
        const __bf16* kp = kbase + (long)(tj * 64 + jb * 16 + l16) * NQKV + quad * 8;
        bf16x8 b0 = *(const bf16x8*)kp, b1 = *(const bf16x8*)(kp + 32);
        f32x4 acc = {};
        acc = mfma16(a0, b0, acc);
        acc = mfma16(a1, b1, acc);
        const int j = tj * 64 + jb * 16 + l16;
        float colsum = 0.0f;
#pragma unroll
        for (int r = 0; r < 4; r++) {
            const int i = i0 + quad * 4 + r;
            float v = fmaxf(acc[r] * 0.125f, 0.0f);
            v = (j >= 1 && j < i) ? v : 0.0f;
            S[((long)b * TT + i) * TT + j] = (__bf16)v;
            colsum += v;
        }
        colsum += __shfl_xor(colsum, 16);
        colsum += __shfl_xor(colsum, 32);
        if (quad == 0)
            atomicAdd(&csum[((long)b * NCH + chunk) * TT + j], colsum);
    }
}

// ---------------------------------------------------------------------------
// 4) Exclusive cumsum over query dim: single pass (prefix folded in),
//    early-exit right of the diagonal.
// ---------------------------------------------------------------------------
__global__ __launch_bounds__(256) void scan_write_kernel(
    const __bf16* __restrict__ S, const float* __restrict__ csum, __bf16* __restrict__ Fo)
{
    const int chunk = blockIdx.y, b = blockIdx.z;
    const int ib = chunk * CH;
    const int j0 = blockIdx.x * 256;
    if (j0 >= ib + CH) return;                 // F[j > i] never read unmasked
    const int j = j0 + threadIdx.x;
    float off = 0.0f;
    for (int c = 0; c < chunk; c++) off += csum[((long)b * NCH + c) * TT + j];
    const __bf16* ps = S  + ((long)b * TT + ib) * TT + j;
    __bf16*       pf = Fo + ((long)b * TT + ib) * TT + j;
#pragma unroll
    for (int ii = 0; ii < CH; ii++) {
        float v = ((ib + ii) > j) ? (float)ps[(long)ii * TT] : 0.0f;
        pf[(long)ii * TT] = (__bf16)off;   // exclusive: write before add
        off += v;
    }
}

// ---------------------------------------------------------------------------
// 5) Flash attention with F subtraction. v10: 1536 SINGLE-TILE BLOCKS.
//    gid -> xs = gid&7 (XCD slot: keeps R9's verified L2 clustering, 3 (b,h)
//    groups/slot = 1.5 MB), qt = 63 - (gid>>3)/3 (big-first LPT within XCD),
//    group = xs + 8*((gid>>3)%3). 2x the blocks of R9 -> LDS-capped 4
//    blocks/CU = 8 waves/CU for real latency overlap. Keeps the dbuf
//    single-barrier pipeline (stage next tile right after barrier).
// ---------------------------------------------------------------------------
__global__ __launch_bounds__(128, 2) void flash_kernel(
    const __bf16* __restrict__ qkv, const __bf16* __restrict__ vT,
    const __bf16* __restrict__ F, __bf16* __restrict__ y)
{
    __shared__ __align__(16) __bf16 Ks[2][64 * 64];
    __shared__ __align__(16) __bf16 Vs[2][64 * 64];
    __shared__ __align__(16) __bf16 Pls[2][16 * 72];
    const int gid = blockIdx.x;
    const int xs = gid & 7, r9 = gid >> 3;
    const int qt = 63 - r9 / 3;               // big-first within XCD
    const int gi = xs + ((r9 % 3) << 3);      // (b,h) group 0..23, XCD-resident
    const int h = gi % 12, b = gi / 12;
    const int w = threadIdx.x >> 6, lane = threadIdx.x & 63, quad = lane >> 4, l16 = lane & 15;
    const int rl = lane >> 3;                 // DMA: row-in-group 0..7
    const int cs8 = ((lane & 7) ^ rl) * 8;    // DMA: swizzled source col offset
    const int sw0 = ((quad)     ^ (l16 & 7)) * 8;   // reader swizzle
    const int sw1 = ((quad + 4) ^ (l16 & 7)) * 8;
    __bf16* Pl = &Pls[w][0];
    const __bf16* kb = qkv + (long)(b * TT) * NQKV + 768 + h * 64;   // + j*NQKV
    const __bf16* vb = vT + ((long)(b * HH + h) << 6) * TT;          // [d][t]
    const __bf16* Fbase = F + (long)b * TT * TT;

    const int i0 = qt * 32 + w * 16;
    const __bf16* qp = qkv + (long)(b * TT + i0 + l16) * NQKV + h * 64 + quad * 8;
    const bf16x8 aq0 = *(const bf16x8*)qp;
    const bf16x8 aq1 = *(const bf16x8*)(qp + 32);
    const __bf16* Fb = Fbase + (long)i0 * TT;

    f32x4 O[4] = {};
    float lr[4] = {0.0f, 0.0f, 0.0f, 0.0f};
    __bf16 Fn[4][4];
    const int jtend = (qt >> 1) << 6;

    // ---- prologue: stage jt=0 into buf 0 + F(jt=0) ----
    {
        __bf16* KsW = Ks[0] + w * 2048;
        __bf16* VsW = Vs[0] + w * 2048;
#pragma unroll
        for (int t = 0; t < 4; t++)
            load_lds16(kb + (long)(w * 32 + t * 8 + rl) * NQKV + cs8, KsW + t * 512);
#pragma unroll
        for (int t = 0; t < 4; t++)
            load_lds16(vb + (long)(w * 32 + t * 8 + rl) * TT + cs8, VsW + t * 512);
#pragma unroll
        for (int jh = 0; jh < 4; jh++)
#pragma unroll
            for (int r = 0; r < 4; r++)
                Fn[jh][r] = Fb[(long)(quad * 4 + r) * TT + jh * 16 + l16];
    }

    for (int jt = 0; jt <= jtend; jt += 64) {
        const int buf = (jt >> 6) & 1;
        __syncthreads();   // drains staging of Ks/Vs[buf] + Fn loads

        __bf16 Fc[4][4];
#pragma unroll
        for (int jh = 0; jh < 4; jh++)
#pragma unroll
            for (int r = 0; r < 4; r++)
                Fc[jh][r] = Fn[jh][r];

        // ---- issue next iter's staging + F (in flight through compute) ----
        if (jt + 64 <= jtend) {
            const int jt2 = jt + 64;
            __bf16* KsW = Ks[buf ^ 1] + w * 2048;
            __bf16* VsW = Vs[buf ^ 1] + w * 2048;
#pragma unroll
            for (int t = 0; t < 4; t++)
                load_lds16(kb + (long)(jt2 + w * 32 + t * 8 + rl) * NQKV + cs8, KsW + t * 512);
#pragma unroll
            for (int t = 0; t < 4; t++)
                load_lds16(vb + (long)(w * 32 + t * 8 + rl) * TT + jt2 + cs8, VsW + t * 512);
#pragma unroll
            for (int jh = 0; jh < 4; jh++)
#pragma unroll
                for (int r = 0; r < 4; r++)
                    Fn[jh][r] = Fb[(long)(quad * 4 + r) * TT + jt2 + jh * 16 + l16];
        }
        __builtin_amdgcn_sched_barrier(0);   // pin issue point

        // ---- QK from LDS (cur buffer) ----
        const __bf16* Kc = Ks[buf];
        const __bf16* Vc = Vs[buf];
        float sc[4][4];
#pragma unroll
        for (int jh = 0; jh < 4; jh++) {
            const int jr = jh * 16 + l16;
            const bf16x8 kc0 = *(const bf16x8*)(Kc + (jr << 6) + sw0);
            const bf16x8 kc1 = *(const bf16x8*)(Kc + (jr << 6) + sw1);
            f32x4 acc = {};
            acc = mfma16(aq0, kc0, acc);
            acc = mfma16(aq1, kc1, acc);
#pragma unroll
            for (int r = 0; r < 4; r++) sc[jh][r] = acc[r];
        }
        // ---- softmax terms ----
        if (jt == jtend) {           // diagonal tile: causal mask
#pragma unroll
            for (int jh = 0; jh < 4; jh++) {
                const int j = jt + jh * 16 + l16;
#pragma unroll
                for (int r = 0; r < 4; r++) {
                    const int i = i0 + quad * 4 + r;
                    float v = fmaf(sc[jh][r], 0.125f, -(float)Fc[jh][r]);
                    v = (j <= i) ? v : -35.0f;
                    const float p = __expf(v);
                    sc[jh][r] = p;
                    lr[r] += p;
                }
            }
        } else {
#pragma unroll
            for (int jh = 0; jh < 4; jh++) {
#pragma unroll
                for (int r = 0; r < 4; r++) {
                    float v = fmaf(sc[jh][r], 0.125f, -(float)Fc[jh][r]);
                    const float p = __expf(v);
                    sc[jh][r] = p;
                    lr[r] += p;
                }
            }
        }
        // ---- P -> LDS (C-layout -> row-major), wave-private ----
#pragma unroll
        for (int r = 0; r < 4; r++) {
            const int il = quad * 4 + r;
#pragma unroll
            for (int jh = 0; jh < 4; jh++)
                Pl[il * 72 + jh * 16 + l16] = (__bf16)sc[jh][r];
        }
        const bf16x8 ap0 = *(const bf16x8*)(Pl + l16 * 72 + quad * 8);
        const bf16x8 ap1 = *(const bf16x8*)(Pl + l16 * 72 + 32 + quad * 8);
        // ---- PV from LDS (cur buffer) ----
#pragma unroll
        for (int db = 0; db < 4; db++) {
            const bf16x8 vv0 = *(const bf16x8*)(Vc + ((db * 16 + l16) << 6) + sw0);
            const bf16x8 vv1 = *(const bf16x8*)(Vc + ((db * 16 + l16) << 6) + sw1);
            O[db] = mfma16(ap0, vv0, O[db]);
            O[db] = mfma16(ap1, vv1, O[db]);
        }
    }

    // finalize
    float inv[4];
#pragma unroll
    for (int r = 0; r < 4; r++) {
        float s2 = lr[r];
#pragma unroll
        for (int off = 8; off >= 1; off >>= 1) s2 += __shfl_xor(s2, off, 16);
        inv[r] = 1.0f / s2;
    }
#pragma unroll
    for (int db = 0; db < 4; db++) {
#pragma unroll
        for (int r = 0; r < 4; r++) {
            const int i = i0 + quad * 4 + r;
            y[((long)(b * TT + i)) * (HH * DD) + h * 64 + db * 16 + l16] = (__bf16)(O[db][r] * inv[r]);
        }
    }
}

// ---------------------------------------------------------------------------
extern "C" void kernel_launch(void* const* d_in, const int* in_sizes, int n_in,
                              void* d_out, int out_size, void* d_ws, size_t ws_size,
                              hipStream_t stream)
{
    const float* x      = (const float*)d_in[0];
    const float* w_attn = (const float*)d_in[1];
    const float* b_attn = (const float*)d_in[2];
    const float* w_proj = (const float*)d_in[3];
    const float* b_proj = (const float*)d_in[4];
    float* out = (float*)d_out;

    char* ws = (char*)d_ws;
    __bf16* xb   = (__bf16*)ws; ws += (long)MTOT * CC * 2;
    __bf16* wab  = (__bf16*)ws; ws += (long)NQKV * CC * 2;
    __bf16* wpb  = (__bf16*)ws; ws += (long)CC * (HH*DD) * 2;
    __bf16* qkvb = (__bf16*)ws; ws += (long)MTOT * NQKV * 2;        // 18.9 MB (v third unused)
    __bf16* vtb  = (__bf16*)ws; ws += (long)BB * HH * TT * DD * 2;
    __bf16* SF   = (__bf16*)ws; ws += (long)BB * TT * TT * 2;       // S (bf16)
    __bf16* Fo   = (__bf16*)ws; ws += (long)BB * TT * TT * 2;       // F (bf16)
    float*  cs   = (float*)ws;  ws += (long)BB * NCH * TT * 4;      // 1 MB
    __bf16* yb   = (__bf16*)ws; ws += (long)MTOT * (HH*DD) * 2;

    // 1) convert inputs to bf16 + zero csum (fused)
    cvt_bf16_kernel<<<5376 + 256, 256, 0, stream>>>(x, w_attn, w_proj, xb, wab, wpb, cs);
    // 2) QKV projection -> qkv (q/k) + vT (v, fused transpose)
    gemm_nt_kernel<0><<<dim3(NQKV / 128, MTOT / 128), 256, 0, stream>>>(
        xb, wab, b_attn, qkvb, vtb, nullptr, CC);
    // 3) head-0 selection scores S (bf16) + fused chunk-sums -> csum
    sgemm_kernel<<<dim3(TT / 64, TT / 64, BB), 256, 0, stream>>>(qkvb, SF, cs);
    // 4) exclusive cumsum over query dim -> F (bf16), single pass
    scan_write_kernel<<<dim3(TT / 256, NCH, BB), 256, 0, stream>>>(SF, cs, Fo);
    // 5) flash attention -> y (bf16); 1536 XCD-clustered LPT blocks
    flash_kernel<<<dim3(1536), 128, 0, stream>>>(qkvb, vtb, Fo, yb);
    // 6) output projection -> out (f32)
    gemm_nt_kernel<1><<<dim3(CC / 128, MTOT / 128), 256, 0, stream>>>(
        yb, wpb, b_proj, nullptr, nullptr, out, HH * DD);
}